// Round 4
// baseline (173.288 us; speedup 1.0000x reference)
//
#include <hip/hip_runtime.h>
#include <hip/hip_cooperative_groups.h>

namespace cg = cooperative_groups;

#define BSZ 2
#define NN  512
#define DD  128

// All f32. Algorithm: exp(k+B) = exp(B)*exp(k); stabilizing max cancels in
// num/den. Two [512x512]@[512x256] f32 GEMMs instead of 67M broadcast exps.
//
// Single cooperative kernel (256 blocks x 256 threads = 1 block/CU, trivially
// co-resident), grid.sync() between phases. Fallback: 3 plain launches if the
// cooperative launch is rejected (e.g. under graph capture) — identical math.

// ---------------- Phase 1: QKV rows + transforms, eb = exp(B) ----------------
__device__ __forceinline__ void phase1(
    int blk, int tid,
    const float* __restrict__ x,
    const float* __restrict__ Wq, const float* __restrict__ bq,
    const float* __restrict__ Wk, const float* __restrict__ bk,
    const float* __restrict__ Wv, const float* __restrict__ bv,
    const float* __restrict__ Bm,
    float* __restrict__ qs, float* __restrict__ ekc, float* __restrict__ eb)
{
    __shared__ float xs[4][DD];
    const int r0 = blk * 4;                       // 4 rows/block, 1024 rows
    #pragma unroll
    for (int u = 0; u < 2; ++u) {
        const int idx = u * 256 + tid;            // 0..511
        xs[idx >> 7][idx & 127] = x[(size_t)r0 * DD + idx];
    }
    __syncthreads();

    const int col = tid & 127;
    const int rh  = (tid >> 7) * 2;               // this thread: rows rh, rh+1

    float aq0 = bq[col], ak0 = bk[col], av0 = bv[col];
    float aq1 = aq0, ak1 = ak0, av1 = av0;
    #pragma unroll 4
    for (int d = 0; d < DD; ++d) {
        const float wq = Wq[d * DD + col];
        const float wk = Wk[d * DD + col];
        const float wv = Wv[d * DD + col];
        const float x0 = xs[rh][d], x1 = xs[rh + 1][d];
        aq0 = fmaf(x0, wq, aq0);  aq1 = fmaf(x1, wq, aq1);
        ak0 = fmaf(x0, wk, ak0);  ak1 = fmaf(x1, wk, ak1);
        av0 = fmaf(x0, wv, av0);  av1 = fmaf(x1, wv, av1);
    }
    const int m = r0 + rh;
    const float ek0 = __expf(ak0), ek1 = __expf(ak1);
    qs[(size_t)m * DD + col]       = 1.0f / (1.0f + __expf(-aq0));
    qs[(size_t)(m + 1) * DD + col] = 1.0f / (1.0f + __expf(-aq1));
    float* b0 = ekc + (size_t)m * (2 * DD);
    b0[col]      = ek0 * av0;
    b0[DD + col] = ek0;
    float* b1 = ekc + (size_t)(m + 1) * (2 * DD);
    b1[col]      = ek1 * av1;
    b1[DD + col] = ek1;

    // eb = exp(B): 65536 float4 over 65536 threads, 1 each
    const int i = blk * 256 + tid;
    float4 v = ((const float4*)Bm)[i];
    v.x = __expf(v.x); v.y = __expf(v.y); v.z = __expf(v.z); v.w = __expf(v.w);
    ((float4*)eb)[i] = v;
}

// -------- Phase 2: partial GEMM part[jc][b][i][c] over j-chunk jc ----------
__device__ __forceinline__ void phase2(
    int blk, int tid,
    const float* __restrict__ eb, const float* __restrict__ ekc,
    float* __restrict__ pnum, float* __restrict__ pden)
{
    const int b  = blk & 1;
    const int it = (blk >> 1) & 31;
    const int jc = blk >> 6;                      // 0..3
    const int c  = tid;                           // 0..255
    const int i0 = it * 16;
    const int j0 = jc * 128;

    const float* src = ekc + ((size_t)b * NN + j0) * (2 * DD) + c;
    const float* ebp = eb + (size_t)i0 * NN + j0;

    float acc[16];
    #pragma unroll
    for (int ii = 0; ii < 16; ++ii) acc[ii] = 0.0f;

    for (int j = 0; j < 128; j += 4) {
        const float w0 = src[0 * 2 * DD];
        const float w1 = src[1 * 2 * DD];
        const float w2 = src[2 * 2 * DD];
        const float w3 = src[3 * 2 * DD];
        src += 4 * 2 * DD;
        #pragma unroll
        for (int ii = 0; ii < 16; ++ii) {
            const float4 e = *(const float4*)(ebp + (size_t)ii * NN + j);
            acc[ii] = fmaf(e.w, w3, fmaf(e.z, w2, fmaf(e.y, w1, fmaf(e.x, w0, acc[ii]))));
        }
    }

    float*       dst = (c < DD) ? pnum : pden;
    const int    d   = c & (DD - 1);
    const size_t o   = ((size_t)jc * BSZ + b) * NN * DD + (size_t)i0 * DD + d;
    #pragma unroll
    for (int ii = 0; ii < 16; ++ii)
        dst[o + (size_t)ii * DD] = acc[ii];
}

// ---------------- Phase 3: reduce partials + finalize ----------------
__device__ __forceinline__ void phase3(
    int blk, int tid,
    const float* __restrict__ qs, const float* __restrict__ pnum,
    const float* __restrict__ pden, float* __restrict__ out)
{
    const int S = BSZ * NN * DD;                  // 131072
    #pragma unroll
    for (int u = 0; u < 2; ++u) {
        const int idx = blk * 512 + u * 256 + tid;
        const float n0 = pnum[idx] + pnum[idx + S] + pnum[idx + 2 * S] + pnum[idx + 3 * S];
        const float d0 = pden[idx] + pden[idx + S] + pden[idx + 2 * S] + pden[idx + 3 * S];
        out[idx] = qs[idx] * n0 / d0;
    }
}

// ---------------- fused cooperative kernel ----------------
__global__ __launch_bounds__(256) void aft_fused(
    const float* __restrict__ x,
    const float* __restrict__ Wq, const float* __restrict__ bq,
    const float* __restrict__ Wk, const float* __restrict__ bk,
    const float* __restrict__ Wv, const float* __restrict__ bv,
    const float* __restrict__ Bm,
    float* __restrict__ qs, float* __restrict__ ekc, float* __restrict__ eb,
    float* __restrict__ pnum, float* __restrict__ pden,
    float* __restrict__ out)
{
    cg::grid_group grid = cg::this_grid();
    const int blk = blockIdx.x, tid = threadIdx.x;
    phase1(blk, tid, x, Wq, bq, Wk, bk, Wv, bv, Bm, qs, ekc, eb);
    grid.sync();
    phase2(blk, tid, eb, ekc, pnum, pden);
    grid.sync();
    phase3(blk, tid, qs, pnum, pden, out);
}

// ---------------- fallback plain kernels ----------------
__global__ __launch_bounds__(256) void aft_p1(
    const float* __restrict__ x,
    const float* __restrict__ Wq, const float* __restrict__ bq,
    const float* __restrict__ Wk, const float* __restrict__ bk,
    const float* __restrict__ Wv, const float* __restrict__ bv,
    const float* __restrict__ Bm,
    float* __restrict__ qs, float* __restrict__ ekc, float* __restrict__ eb)
{
    phase1(blockIdx.x, threadIdx.x, x, Wq, bq, Wk, bk, Wv, bv, Bm, qs, ekc, eb);
}

__global__ __launch_bounds__(256) void aft_p2(
    const float* __restrict__ eb, const float* __restrict__ ekc,
    float* __restrict__ pnum, float* __restrict__ pden)
{
    phase2(blockIdx.x, threadIdx.x, eb, ekc, pnum, pden);
}

__global__ __launch_bounds__(256) void aft_p3(
    const float* __restrict__ qs, const float* __restrict__ pnum,
    const float* __restrict__ pden, float* __restrict__ out)
{
    phase3(blockIdx.x, threadIdx.x, qs, pnum, pden, out);
}

extern "C" void kernel_launch(void* const* d_in, const int* in_sizes, int n_in,
                              void* d_out, int out_size, void* d_ws, size_t ws_size,
                              hipStream_t stream) {
    const float* x  = (const float*)d_in[0];
    const float* Wq = (const float*)d_in[1];
    const float* bq = (const float*)d_in[2];
    const float* Wk = (const float*)d_in[3];
    const float* bk = (const float*)d_in[4];
    const float* Wv = (const float*)d_in[5];
    const float* bv = (const float*)d_in[6];
    const float* Bm = (const float*)d_in[7];
    float* out = (float*)d_out;

    // ws partition (floats): qs | ekc | eb | pnum | pden  (~6.8 MB used)
    float* qs   = (float*)d_ws;
    float* ekc  = qs   + (size_t)BSZ * NN * DD;        // 131072
    float* eb   = ekc  + (size_t)BSZ * NN * 2 * DD;    // 262144
    float* pnum = eb   + (size_t)NN * NN;              // 262144
    float* pden = pnum + (size_t)4 * BSZ * NN * DD;    // 524288

    void* args[] = { (void*)&x, (void*)&Wq, (void*)&bq, (void*)&Wk, (void*)&bk,
                     (void*)&Wv, (void*)&bv, (void*)&Bm, (void*)&qs, (void*)&ekc,
                     (void*)&eb, (void*)&pnum, (void*)&pden, (void*)&out };

    hipError_t err = hipLaunchCooperativeKernel(
        (const void*)aft_fused, dim3(256), dim3(256), args, 0, stream);

    if (err != hipSuccess) {
        // Fallback: identical math as 3 plain launches.
        aft_p1<<<dim3(256), dim3(256), 0, stream>>>(
            x, Wq, bq, Wk, bk, Wv, bv, Bm, qs, ekc, eb);
        aft_p2<<<dim3(256), dim3(256), 0, stream>>>(eb, ekc, pnum, pden);
        aft_p3<<<dim3(256), dim3(256), 0, stream>>>(qs, pnum, pden, out);
    }
}

// Round 5
// 98.616 us; speedup vs baseline: 1.7572x; 1.7572x over previous
//
#include <hip/hip_runtime.h>

#define BSZ 2
#define NN  512
#define DD  128

// All f32. Algorithm: exp(k+B) = exp(B)*exp(k); the stabilizing max cancels
// in num/den. Two [512x512]@[512x256] f32 GEMMs instead of 67M broadcast exps.
//
// R4 post-mortem: cooperative grid.sync() costs ~35 us/sync on MI355X
// (device-scope barrier across 8 non-coherent XCD L2s) — 3 plain launches in
// the captured graph are far cheaper. Harness re-poison fills (~91 us) are a
// fixed floor in the timed path; our kernels are the remaining ~13 us -> ~6.

// ---------------------------------------------------------------------------
// K1: 256 blocks x 256 threads.
//   QKV for 4 rows/block (2 rows/thread), plus eb = exp(B) (one float4/thread).
// Outputs (f32 in ws):
//   qs  [BSZ][NN][DD]     sigmoid(q)
//   ekc [BSZ][NN][2*DD]   c<128: exp(k)*v ; c>=128: exp(k)
//   eb  [NN][NN]          exp(B)
// ---------------------------------------------------------------------------
__global__ __launch_bounds__(256) void aft_p1(
    const float* __restrict__ x,
    const float* __restrict__ Wq, const float* __restrict__ bq,
    const float* __restrict__ Wk, const float* __restrict__ bk,
    const float* __restrict__ Wv, const float* __restrict__ bv,
    const float* __restrict__ Bm,
    float* __restrict__ qs, float* __restrict__ ekc, float* __restrict__ eb)
{
    const int blk = blockIdx.x;
    const int tid = threadIdx.x;

    __shared__ float xs[4][DD];
    const int r0 = blk * 4;                       // 4 rows/block, 1024 rows
    #pragma unroll
    for (int u = 0; u < 2; ++u) {
        const int idx = u * 256 + tid;            // 0..511
        xs[idx >> 7][idx & 127] = x[(size_t)r0 * DD + idx];
    }
    __syncthreads();

    const int col = tid & 127;
    const int rh  = (tid >> 7) * 2;               // this thread: rows rh, rh+1

    float aq0 = bq[col], ak0 = bk[col], av0 = bv[col];
    float aq1 = aq0, ak1 = ak0, av1 = av0;
    #pragma unroll 4
    for (int d = 0; d < DD; ++d) {
        const float wq = Wq[d * DD + col];
        const float wk = Wk[d * DD + col];
        const float wv = Wv[d * DD + col];
        const float x0 = xs[rh][d], x1 = xs[rh + 1][d];
        aq0 = fmaf(x0, wq, aq0);  aq1 = fmaf(x1, wq, aq1);
        ak0 = fmaf(x0, wk, ak0);  ak1 = fmaf(x1, wk, ak1);
        av0 = fmaf(x0, wv, av0);  av1 = fmaf(x1, wv, av1);
    }
    const int m = r0 + rh;
    const float ek0 = __expf(ak0), ek1 = __expf(ak1);
    qs[(size_t)m * DD + col]       = 1.0f / (1.0f + __expf(-aq0));
    qs[(size_t)(m + 1) * DD + col] = 1.0f / (1.0f + __expf(-aq1));
    float* b0 = ekc + (size_t)m * (2 * DD);
    b0[col]      = ek0 * av0;
    b0[DD + col] = ek0;
    float* b1 = ekc + (size_t)(m + 1) * (2 * DD);
    b1[col]      = ek1 * av1;
    b1[DD + col] = ek1;

    // eb = exp(B): 65536 float4 over 65536 threads, 1 each
    const int i = blk * 256 + tid;
    float4 v = ((const float4*)Bm)[i];
    v.x = __expf(v.x); v.y = __expf(v.y); v.z = __expf(v.z); v.w = __expf(v.w);
    ((float4*)eb)[i] = v;
}

// ---------------------------------------------------------------------------
// K2: partial GEMM part[jc][b][i][c] = sum_{j in chunk jc} eb[i][j]*ekc[b][j][c]
// Grid 512 = (b:2) x (itile:64, 8 rows) x (jchunk:4); block 256 threads.
// 2 blocks/CU = 8 waves/CU for latency hiding. Thread = one column c, 8 i-rows
// in registers. eb reads are wave-uniform; ekc reads one coalesced dword per j.
// ---------------------------------------------------------------------------
__global__ __launch_bounds__(256) void aft_p2(
    const float* __restrict__ eb, const float* __restrict__ ekc,
    float* __restrict__ pnum, float* __restrict__ pden)
{
    const int blk = blockIdx.x;
    const int b   = blk & 1;
    const int it  = (blk >> 1) & 63;
    const int jc  = blk >> 7;          // 0..3
    const int c   = threadIdx.x;       // 0..255
    const int i0  = it * 8;
    const int j0  = jc * 128;

    const float* src = ekc + ((size_t)b * NN + j0) * (2 * DD) + c;
    const float* ebp = eb + (size_t)i0 * NN + j0;

    float acc[8];
    #pragma unroll
    for (int ii = 0; ii < 8; ++ii) acc[ii] = 0.0f;

    for (int j = 0; j < 128; j += 4) {
        const float w0 = src[0 * 2 * DD];
        const float w1 = src[1 * 2 * DD];
        const float w2 = src[2 * 2 * DD];
        const float w3 = src[3 * 2 * DD];
        src += 4 * 2 * DD;
        #pragma unroll
        for (int ii = 0; ii < 8; ++ii) {
            const float4 e = *(const float4*)(ebp + (size_t)ii * NN + j);
            acc[ii] = fmaf(e.w, w3, fmaf(e.z, w2, fmaf(e.y, w1, fmaf(e.x, w0, acc[ii]))));
        }
    }

    float*       dst = (c < DD) ? pnum : pden;
    const int    d   = c & (DD - 1);
    const size_t o   = ((size_t)jc * BSZ + b) * NN * DD + (size_t)i0 * DD + d;
    #pragma unroll
    for (int ii = 0; ii < 8; ++ii)
        dst[o + (size_t)ii * DD] = acc[ii];
}

// ---------------------------------------------------------------------------
// K3: out = qs * (sum pnum) / (sum pden); 256 blocks x 256 thr x 2 elems
// ---------------------------------------------------------------------------
__global__ __launch_bounds__(256) void aft_p3(
    const float* __restrict__ qs, const float* __restrict__ pnum,
    const float* __restrict__ pden, float* __restrict__ out)
{
    const int S = BSZ * NN * DD;                  // 131072
    #pragma unroll
    for (int u = 0; u < 2; ++u) {
        const int idx = blockIdx.x * 512 + u * 256 + threadIdx.x;
        const float n0 = pnum[idx] + pnum[idx + S] + pnum[idx + 2 * S] + pnum[idx + 3 * S];
        const float d0 = pden[idx] + pden[idx + S] + pden[idx + 2 * S] + pden[idx + 3 * S];
        out[idx] = qs[idx] * n0 / d0;
    }
}

extern "C" void kernel_launch(void* const* d_in, const int* in_sizes, int n_in,
                              void* d_out, int out_size, void* d_ws, size_t ws_size,
                              hipStream_t stream) {
    const float* x  = (const float*)d_in[0];
    const float* Wq = (const float*)d_in[1];
    const float* bq = (const float*)d_in[2];
    const float* Wk = (const float*)d_in[3];
    const float* bk = (const float*)d_in[4];
    const float* Wv = (const float*)d_in[5];
    const float* bv = (const float*)d_in[6];
    const float* Bm = (const float*)d_in[7];
    float* out = (float*)d_out;

    // ws partition (floats): qs | ekc | eb | pnum | pden  (~6.8 MB used)
    float* qs   = (float*)d_ws;
    float* ekc  = qs   + (size_t)BSZ * NN * DD;        // 131072
    float* eb   = ekc  + (size_t)BSZ * NN * 2 * DD;    // 262144
    float* pnum = eb   + (size_t)NN * NN;              // 262144
    float* pden = pnum + (size_t)4 * BSZ * NN * DD;    // 524288

    aft_p1<<<dim3(256), dim3(256), 0, stream>>>(
        x, Wq, bq, Wk, bk, Wv, bv, Bm, qs, ekc, eb);
    aft_p2<<<dim3(512), dim3(256), 0, stream>>>(eb, ekc, pnum, pden);
    aft_p3<<<dim3(256), dim3(256), 0, stream>>>(qs, pnum, pden, out);
}